// Round 8
// baseline (770.963 us; speedup 1.0000x reference)
//
#include <hip/hip_runtime.h>
#include <hip/hip_bf16.h>

// RGCN segment MM:  out[d] = sum_r ( sum_{e: dst=d, et=r} feat[src[e]] ) @ W[r]
// Bucket = (dst>>7)*R + et (6256 buckets) built by one bump-allocator scatter
// (rec = src | dl<<sbits). Fused kernel: 512-thread blocks (8 waves, 2x4 wave
// grid), per (block of 128 dst, r):
//   per 128-edge chunk: edge-PAIR gathers packed to u32 -> feat-major Gt
//     (XOR-swizzled (eblk^cc), both sides verified), then
//     AGGREGATE: accST[feat][dst] += Gt-rows(A,b128) @ onehot(B,regs)  [2 bar]
//   then once per r: pack accST -> Ssm[dst][feat] (b64, swizzled, aliased on
//   Gt) and PROJECT: acc^T[of][dst] += W[r](A, global L2-hot) @ Ssm(B, b128).
// acc held across r; epilogue = float4 stores of out rows.
//
// R8 lesson: 4 barrier-phases/chunk at 2 waves/SIMD (reg wall: acc64+Ta64)
// = latency-serialized (all counters <30%). R9: 8-wave blocks halve per-wave
// acc state (~120 regs -> 4 waves/SIMD, 16 waves/CU), aggregate-first halves
// phases (2 bar/chunk) and per-chunk MFMA; one projection GEMM per r.

#define FEAT 128
#define CAP 512          // records per bucket (lambda~256, 16 sigma headroom)
#define CHUNK 128

typedef __attribute__((ext_vector_type(8))) short short8;
typedef __attribute__((ext_vector_type(8))) __bf16 bf16x8;
typedef __attribute__((ext_vector_type(4))) float f32x4;
typedef __attribute__((ext_vector_type(2))) unsigned int uint2v;

__device__ __forceinline__ unsigned f2bf(float x) {
    union { float f; unsigned u; } v; v.f = x;
    unsigned r = v.u + 0x7FFFu + ((v.u >> 16) & 1u);   // RNE
    return r >> 16;
}

// ---------------- conversions ----------------
__global__ void cvt_feat_kernel(const float* __restrict__ f,
                                ushort* __restrict__ o, int n8) {
    int i = blockIdx.x * blockDim.x + threadIdx.x;
    if (i >= n8) return;
    const float4* f4 = (const float4*)f;
    float4 a = f4[2 * i], b = f4[2 * i + 1];
    union { ushort u[8]; int4 v; } pk;
    pk.u[0] = f2bf(a.x); pk.u[1] = f2bf(a.y); pk.u[2] = f2bf(a.z); pk.u[3] = f2bf(a.w);
    pk.u[4] = f2bf(b.x); pk.u[5] = f2bf(b.y); pk.u[6] = f2bf(b.z); pk.u[7] = f2bf(b.w);
    ((int4*)o)[i] = pk.v;
}

// W[r][k][n] fp32 -> wt[r][n][k] bf16 (n-major, k-contig per of-row)
__global__ void cvt_w_kernel(const float* __restrict__ w,
                             ushort* __restrict__ wt, int total) {
    int i = blockIdx.x * blockDim.x + threadIdx.x;
    if (i >= total) return;
    int r = i >> 14, n = (i >> 7) & 127, k = i & 127;
    wt[i] = (ushort)f2bf(w[(r << 14) + (k << 7) + n]);
}

// ---------------- bucketize edges (bump allocator) ----------------
__global__ void scatter_kernel(const int* __restrict__ dst,
                               const int* __restrict__ et,
                               const int* __restrict__ src, int E, int R,
                               int sbits, int* __restrict__ cursor,
                               int* __restrict__ recs) {
    int i = blockIdx.x * blockDim.x + threadIdx.x;
    int stride = gridDim.x * blockDim.x;
    for (; i < E; i += stride) {
        int d = dst[i];
        int b = (d >> 7) * R + et[i];
        int p = atomicAdd(&cursor[b], 1);
        if (p < CAP) recs[(size_t)b * CAP + p] = src[i] | ((d & 127) << sbits);
    }
}

// ---------------- fused aggregate + project ----------------
__global__ __launch_bounds__(512, 4)
void fused_kernel(const ushort* __restrict__ featb,
                  const ushort* __restrict__ wtr,
                  const int* __restrict__ recs,
                  const int* __restrict__ cursor,
                  float* __restrict__ out, int N, int R, int sbits) {
    __shared__ __align__(16) ushort GS[128 * 128];  // Gt[feat][edge] / Ssm, aliased
    __shared__ __align__(16) ushort dlv[CHUNK];     // dst-low per edge slot

    int t = threadIdx.x;
    int lane = t & 63;
    int wid = t >> 6;                      // 0..7
    int lm = lane & 15, lq = lane >> 4;    // MFMA fragment coords
    int wr = wid >> 2;                     // feat/of half (0..1)
    int wc = wid & 3;                      // dst quarter  (0..3)
    int cc = t & 15;                       // staging feat-slice (0..15)
    int pr = t >> 4;                       // staging pair-base (0..31)
    int blk = blockIdx.x, base = blk * 128;
    int smask = (1 << sbits) - 1;

    f32x4 acc[8];                          // acc^T[of][dst], across all r
    #pragma unroll
    for (int i = 0; i < 8; i++) acc[i] = (f32x4){0.f, 0.f, 0.f, 0.f};

    for (int r = 0; r < R; r++) {
        int bkt = blk * R + r;
        int ecnt = cursor[bkt];
        if (ecnt <= 0) continue;           // block-uniform
        if (ecnt > CAP) ecnt = CAP;
        const int* rb = recs + (size_t)bkt * CAP;

        f32x4 accST[8];                    // accST[feat][dst] for this r
        #pragma unroll
        for (int i = 0; i < 8; i++) accST[i] = (f32x4){0.f, 0.f, 0.f, 0.f};

        // ---- prologue: records + gathers for chunk 0 ----
        // thread owns edge-pairs: e(w,par) = 2*(pr+32w)+par, feat slice cc
        int rca[4];
        union { uint4 v; ushort us[8]; } ga[4];
        #pragma unroll
        for (int w = 0; w < 2; w++)
            #pragma unroll
            for (int par = 0; par < 2; par++) {
                int s = w * 2 + par;
                int e = 2 * (pr + 32 * w) + par;
                int rc = (e < ecnt) ? rb[e] : -1;
                rca[s] = rc;
                if (rc >= 0)
                    ga[s].v = *(const uint4*)(featb +
                              (size_t)(rc & smask) * FEAT + cc * 8);
                else
                    ga[s].v = (uint4){0u, 0u, 0u, 0u};
            }

        for (int c0 = 0; c0 < ecnt; c0 += CHUNK) {
            // ---- stage: pack edge-pairs -> Gt[feat][edge] (swizzled) ----
            #pragma unroll
            for (int w = 0; w < 2; w++) {
                int eb8 = (pr >> 2) + 8 * w;            // edge-block 0..15
                int eo = 2 * (pr & 3);                  // pair offset in block
                #pragma unroll
                for (int j = 0; j < 8; j++) {
                    unsigned v = (unsigned)ga[2 * w].us[j] |
                                 ((unsigned)ga[2 * w + 1].us[j] << 16);
                    int f = cc * 8 + j;
                    *(unsigned*)&GS[f * 128 + ((eb8 ^ cc) << 3) + eo] = v;
                }
            }
            if (cc == 0) {
                #pragma unroll
                for (int w = 0; w < 2; w++)
                    #pragma unroll
                    for (int par = 0; par < 2; par++) {
                        int s = w * 2 + par;
                        int e = 2 * (pr + 32 * w) + par;
                        dlv[e] = (rca[s] >= 0)
                            ? (ushort)((rca[s] >> sbits) & 127) : (ushort)0xFF;
                    }
            }
            __syncthreads();                           // A: Gt + dlv ready

            // ---- prefetch next chunk (hides under agg) ----
            bool more = (c0 + CHUNK) < ecnt;
            int rcn[4];
            union { uint4 v; ushort us[8]; } gan[4];
            if (more) {
                #pragma unroll
                for (int w = 0; w < 2; w++)
                    #pragma unroll
                    for (int par = 0; par < 2; par++) {
                        int s = w * 2 + par;
                        int j = c0 + CHUNK + 2 * (pr + 32 * w) + par;
                        int rc = (j < ecnt) ? rb[j] : -1;
                        rcn[s] = rc;
                        if (rc >= 0)
                            gan[s].v = *(const uint4*)(featb +
                                       (size_t)(rc & smask) * FEAT + cc * 8);
                        else
                            gan[s].v = (uint4){0u, 0u, 0u, 0u};
                    }
            }

            // ---- aggregate: accST += Gt(A) @ onehot(B) ----
            #pragma unroll
            for (int ks = 0; ks < 4; ks++) {
                union { ushort u[8]; uint4 v; } dl8;
                dl8.v = *(const uint4*)&dlv[ks * 32 + lq * 8];
                short8 af[4];
                #pragma unroll
                for (int tm = 0; tm < 4; tm++) {
                    int f = wr * 64 + tm * 16 + lm;
                    af[tm] = *(const short8*)&GS[f * 128 +
                             (((ks * 4 + lq) ^ (f >> 3)) << 3)];
                }
                short8 pb[2];
                #pragma unroll
                for (int tn = 0; tn < 2; tn++) {
                    ushort col = (ushort)(wc * 32 + tn * 16 + lm);
                    union { ushort u[8]; short8 s; } b;
                    #pragma unroll
                    for (int q = 0; q < 8; q++)
                        b.u[q] = (dl8.u[q] == col) ? (ushort)0x3F80 : (ushort)0;
                    pb[tn] = b.s;
                }
                #pragma unroll
                for (int tm = 0; tm < 4; tm++)
                    #pragma unroll
                    for (int tn = 0; tn < 2; tn++)
                        accST[tm * 2 + tn] = __builtin_amdgcn_mfma_f32_16x16x32_bf16(
                            __builtin_bit_cast(bf16x8, af[tm]),
                            __builtin_bit_cast(bf16x8, pb[tn]),
                            accST[tm * 2 + tn], 0, 0, 0);
            }
            __syncthreads();                           // B: agg reads done

            if (more) {
                #pragma unroll
                for (int s = 0; s < 4; s++) { rca[s] = rcn[s]; ga[s].v = gan[s].v; }
            }
        }

        // ---- pack accST -> Ssm[dst][feat] (swizzled, aliased on GS) ----
        // C-frag (tm,tn) elem i: feat = wr*64+tm*16+lq*4+i, dst = wc*32+tn*16+lm
        #pragma unroll
        for (int tm = 0; tm < 4; tm++)
            #pragma unroll
            for (int tn = 0; tn < 2; tn++) {
                f32x4 v = accST[tm * 2 + tn];
                union { unsigned u[2]; uint2v w; } pk;
                pk.u[0] = f2bf(v[0]) | (f2bf(v[1]) << 16);
                pk.u[1] = f2bf(v[2]) | (f2bf(v[3]) << 16);
                int dst = wc * 32 + tn * 16 + lm;
                int f4 = wr * 64 + tm * 16 + lq * 4;
                *(uint2v*)&GS[dst * 128 + (((f4 >> 3) ^ (dst & 15)) << 3) +
                              (f4 & 7)] = pk.w;
            }
        __syncthreads();                               // C: Ssm ready

        // ---- project: acc^T += W[r](A, global) @ Ssm(B) ----
        const ushort* wp = wtr + ((size_t)r << 14);
        #pragma unroll
        for (int ks = 0; ks < 4; ks++) {
            short8 aw[4], bs[2];
            #pragma unroll
            for (int tm = 0; tm < 4; tm++) {
                int of = wr * 64 + tm * 16 + lm;
                aw[tm] = *(const short8*)(wp + of * 128 + ks * 32 + lq * 8);
            }
            #pragma unroll
            for (int tn = 0; tn < 2; tn++) {
                int dst = wc * 32 + tn * 16 + lm;
                bs[tn] = *(const short8*)&GS[dst * 128 +
                         (((ks * 4 + lq) ^ (dst & 15)) << 3)];
            }
            #pragma unroll
            for (int tm = 0; tm < 4; tm++)
                #pragma unroll
                for (int tn = 0; tn < 2; tn++)
                    acc[tm * 2 + tn] = __builtin_amdgcn_mfma_f32_16x16x32_bf16(
                        __builtin_bit_cast(bf16x8, aw[tm]),
                        __builtin_bit_cast(bf16x8, bs[tn]),
                        acc[tm * 2 + tn], 0, 0, 0);
        }
        __syncthreads();                               // D: Ssm free for next r
    }

    // ---- epilogue: acc^T frags -> float4 stores ----
    // acc (tm,tn) elem i: of = wr*64+tm*16+lq*4+i, dst = wc*32+tn*16+lm
    #pragma unroll
    for (int tn = 0; tn < 2; tn++) {
        int drow = base + wc * 32 + tn * 16 + lm;
        if (drow < N) {
            #pragma unroll
            for (int tm = 0; tm < 4; tm++) {
                f32x4 v = acc[tm * 2 + tn];
                *(f32x4*)(out + (size_t)drow * FEAT + wr * 64 + tm * 16 + lq * 4) = v;
            }
        }
    }
}

static inline size_t al256(size_t x) { return (x + 255) & ~(size_t)255; }

extern "C" void kernel_launch(void* const* d_in, const int* in_sizes, int n_in,
                              void* d_out, int out_size, void* d_ws,
                              size_t ws_size, hipStream_t stream) {
    const float* feat = (const float*)d_in[0];
    const float* weight = (const float*)d_in[1];
    const int* src = (const int*)d_in[2];
    const int* dst = (const int*)d_in[3];
    const int* et = (const int*)d_in[4];

    int nfeat = in_sizes[0];
    int N = nfeat / FEAT;                    // 100000
    int R = in_sizes[1] / (FEAT * FEAT);     // 8
    int E = in_sizes[2];                     // 1.6M
    int Npad = ((N + 127) / 128) * 128;
    int nblk = Npad / 128;                   // 782
    int NB = nblk * R;                       // 6256 buckets
    float* out = (float*)d_out;

    int sbits = 1;
    while ((1 << sbits) < N) sbits++;        // 17 for N=100000

    // ---- workspace layout (~28 MB) ----
    char* ws = (char*)d_ws;
    size_t o = 0;
    size_t cur_o  = o; o += al256((size_t)NB * 4);
    size_t recs_o = o; o += al256((size_t)NB * CAP * 4);
    size_t wtr_o  = o; o += al256((size_t)R * FEAT * FEAT * 2);
    size_t featb_o = o;

    int* cursor = (int*)(ws + cur_o);
    int* recs   = (int*)(ws + recs_o);
    ushort* wtr   = (ushort*)(ws + wtr_o);
    ushort* featb = (ushort*)(ws + featb_o);

    hipMemsetAsync(cursor, 0, (size_t)NB * 4, stream);

    int wtotal = R * FEAT * FEAT;
    cvt_w_kernel<<<(wtotal + 255) / 256, 256, 0, stream>>>(weight, wtr, wtotal);
    int n8 = nfeat / 8;
    cvt_feat_kernel<<<(n8 + 255) / 256, 256, 0, stream>>>(feat, featb, n8);

    scatter_kernel<<<512, 256, 0, stream>>>(dst, et, src, E, R, sbits,
                                            cursor, recs);

    fused_kernel<<<nblk, 512, 0, stream>>>(featb, wtr, recs, cursor,
                                           out, N, R, sbits);
}

// Round 9
// 583.231 us; speedup vs baseline: 1.3219x; 1.3219x over previous
//
#include <hip/hip_runtime.h>
#include <hip/hip_bf16.h>

// RGCN segment MM:  out[d] = sum_r ( sum_{e: dst=d, et=r} feat[src[e]] ) @ W[r]
// Bucket = (dst>>7)*R + et (6256 buckets) built by one bump-allocator scatter
// (rec = src | dl<<sbits). Fused kernel (256 thr, 4 waves, 64x64 quadrants,
// R3's register/occupancy profile), per (block of 128 dst, r):
//   per 128-edge chunk:
//     stage: edge-QUAD gathers (8x b128) packed -> feat-major Gt[f][e],
//            XOR-swizzled idx = f*128 + (e ^ ((f&7)<<3)), 16x ds_write_b64
//     AGGREGATE: accST[f][dst] += Gt(A, b128 swz reads) @ onehot(B, regs
//            from dlv compares)            [R9-verified pattern, 2 barriers]
//   then once per r: pack accST -> Ssm[dst][f] (R8-verified swizzle formulas,
//   aliased on Gt) and PROJECT: acc^T[of][dst] += wtr[r](A, L2-hot global)
//   @ Ssm(B, b128).  acc held across r; epilogue float4 stores.
//
// R9 lesson: 8-wave + 128 AGPR left 64 arch VGPRs -> 660MB spill traffic;
// b32 pair-pack staging doubled conflicts. R10: back to R3's proven budget
// (~110 VGPR + 128 AGPR, 2 blocks/CU), aggregation via b128/b64 only.
// Scatter: int4 loads + nontemporal rec stores (aux-gap probe, independent).

#define FEAT 128
#define CAP 512          // records per bucket (lambda~256, 16 sigma headroom)
#define CHUNK 128

typedef __attribute__((ext_vector_type(8))) short short8;
typedef __attribute__((ext_vector_type(8))) __bf16 bf16x8;
typedef __attribute__((ext_vector_type(4))) float f32x4;
typedef __attribute__((ext_vector_type(2))) unsigned int uint2v;

union U8x16 { uint4 v; ushort us[8]; };

__device__ __forceinline__ unsigned f2bf(float x) {
    union { float f; unsigned u; } v; v.f = x;
    unsigned r = v.u + 0x7FFFu + ((v.u >> 16) & 1u);   // RNE
    return r >> 16;
}

// ---------------- conversions ----------------
__global__ void cvt_feat_kernel(const float* __restrict__ f,
                                ushort* __restrict__ o, int n8) {
    int i = blockIdx.x * blockDim.x + threadIdx.x;
    if (i >= n8) return;
    const float4* f4 = (const float4*)f;
    float4 a = f4[2 * i], b = f4[2 * i + 1];
    union { ushort u[8]; int4 v; } pk;
    pk.u[0] = f2bf(a.x); pk.u[1] = f2bf(a.y); pk.u[2] = f2bf(a.z); pk.u[3] = f2bf(a.w);
    pk.u[4] = f2bf(b.x); pk.u[5] = f2bf(b.y); pk.u[6] = f2bf(b.z); pk.u[7] = f2bf(b.w);
    ((int4*)o)[i] = pk.v;
}

// W[r][k][n] fp32 -> wt[r][n][k] bf16 (of-major, k contiguous)
__global__ void cvt_w_kernel(const float* __restrict__ w,
                             ushort* __restrict__ wt, int total) {
    int i = blockIdx.x * blockDim.x + threadIdx.x;
    if (i >= total) return;
    int r = i >> 14, n = (i >> 7) & 127, k = i & 127;
    wt[i] = (ushort)f2bf(w[(r << 14) + (k << 7) + n]);
}

// ---------------- bucketize edges (bump allocator) ----------------
__global__ void scatter_kernel(const int* __restrict__ dst,
                               const int* __restrict__ et,
                               const int* __restrict__ src, int E, int R,
                               int sbits, int* __restrict__ cursor,
                               int* __restrict__ recs) {
    int tid = blockIdx.x * blockDim.x + threadIdx.x;
    int stride = gridDim.x * blockDim.x;
    int nq = E >> 2;
    for (int i = tid; i < nq; i += stride) {
        int4 d4 = ((const int4*)dst)[i];
        int4 e4 = ((const int4*)et)[i];
        int4 s4 = ((const int4*)src)[i];
        int dd[4] = {d4.x, d4.y, d4.z, d4.w};
        int ee[4] = {e4.x, e4.y, e4.z, e4.w};
        int ss[4] = {s4.x, s4.y, s4.z, s4.w};
        #pragma unroll
        for (int s = 0; s < 4; s++) {
            int d = dd[s];
            int b = (d >> 7) * R + ee[s];
            int p = atomicAdd(&cursor[b], 1);
            if (p < CAP)
                __builtin_nontemporal_store(ss[s] | ((d & 127) << sbits),
                                            &recs[(size_t)b * CAP + p]);
        }
    }
    for (int i = (nq << 2) + tid; i < E; i += stride) {
        int d = dst[i];
        int b = (d >> 7) * R + et[i];
        int p = atomicAdd(&cursor[b], 1);
        if (p < CAP) recs[(size_t)b * CAP + p] = src[i] | ((d & 127) << sbits);
    }
}

// ---------------- fused aggregate + project ----------------
__global__ __launch_bounds__(256, 2)
void fused_kernel(const ushort* __restrict__ featb,
                  const ushort* __restrict__ wtr,
                  const int* __restrict__ recs,
                  const int* __restrict__ cursor,
                  float* __restrict__ out, int N, int R, int sbits) {
    __shared__ __align__(16) ushort GS[128 * 128];  // Gt[f][e] / Ssm[d][f], aliased
    __shared__ __align__(16) ushort dlv[CHUNK];     // dst-low per edge slot

    int t = threadIdx.x;
    int lane = t & 63, wid = t >> 6;
    int lm = lane & 15, lq = lane >> 4;    // MFMA fragment coords
    int qd = t & 31;                       // staging edge-quad (edges qd*4..+3)
    int fs = t >> 5;                       // staging feat block (feats fs*16..+15)
    int blk = blockIdx.x, base = blk * 128;
    int fqa = (wid >> 1) * 64;             // feat/of quadrant (A rows)
    int dqa = (wid & 1) * 64;              // dst quadrant (B cols)
    int smask = (1 << sbits) - 1;

    f32x4 acc[16];                         // out^T[of][dst], across all r
    #pragma unroll
    for (int i = 0; i < 16; i++) acc[i] = (f32x4){0.f, 0.f, 0.f, 0.f};

    for (int r = 0; r < R; r++) {
        int bkt = blk * R + r;
        int ecnt = cursor[bkt];
        if (ecnt <= 0) continue;           // block-uniform
        if (ecnt > CAP) ecnt = CAP;
        const int* rb = recs + (size_t)bkt * CAP;

        f32x4 accST[16];                   // S^T[f][dst] for this r
        #pragma unroll
        for (int i = 0; i < 16; i++) accST[i] = (f32x4){0.f, 0.f, 0.f, 0.f};

        // ---- prologue: records + gathers for chunk 0 ----
        int rc4[4]; U8x16 ga[4][2];
        #pragma unroll
        for (int s = 0; s < 4; s++) {
            int e = qd * 4 + s;
            int rc = (e < ecnt) ? rb[e] : -1;
            rc4[s] = rc;
            #pragma unroll
            for (int h = 0; h < 2; h++) {
                if (rc >= 0)
                    ga[s][h].v = *(const uint4*)(featb +
                                 (size_t)(rc & smask) * FEAT + fs * 16 + h * 8);
                else
                    ga[s][h].v = (uint4){0u, 0u, 0u, 0u};
            }
        }

        for (int c0 = 0; c0 < ecnt; c0 += CHUNK) {
            // ---- stage: quad-pack -> Gt[f][e], idx = f*128 + (e^((f&7)<<3)) ----
            #pragma unroll
            for (int h = 0; h < 2; h++)
                #pragma unroll
                for (int j = 0; j < 8; j++) {
                    int f = fs * 16 + h * 8 + j;       // f&7 == j
                    unsigned lo = (unsigned)ga[0][h].us[j] |
                                  ((unsigned)ga[1][h].us[j] << 16);
                    unsigned hi = (unsigned)ga[2][h].us[j] |
                                  ((unsigned)ga[3][h].us[j] << 16);
                    uint2v w; w[0] = lo; w[1] = hi;
                    *(uint2v*)&GS[f * 128 + ((qd * 4) ^ (j << 3))] = w;
                }
            if (fs == 0) {
                #pragma unroll
                for (int s = 0; s < 4; s++)
                    dlv[qd * 4 + s] = (rc4[s] >= 0)
                        ? (ushort)((rc4[s] >> sbits) & 127) : (ushort)0xFFFF;
            }
            __syncthreads();                           // A: Gt + dlv ready

            // ---- prefetch next chunk (overlaps aggregate) ----
            bool more = (c0 + CHUNK) < ecnt;
            int rcn[4]; U8x16 gan[4][2];
            if (more) {
                #pragma unroll
                for (int s = 0; s < 4; s++) {
                    int j = c0 + CHUNK + qd * 4 + s;
                    int rc = (j < ecnt) ? rb[j] : -1;
                    rcn[s] = rc;
                    #pragma unroll
                    for (int h = 0; h < 2; h++) {
                        if (rc >= 0)
                            gan[s][h].v = *(const uint4*)(featb +
                                          (size_t)(rc & smask) * FEAT +
                                          fs * 16 + h * 8);
                        else
                            gan[s][h].v = (uint4){0u, 0u, 0u, 0u};
                    }
                }
            }

            // ---- aggregate: accST += Gt(A) @ onehot(B) ----
            #pragma unroll
            for (int ks = 0; ks < 4; ks++) {
                union { ushort u[8]; uint4 v; } dl8;
                dl8.v = *(const uint4*)&dlv[ks * 32 + lq * 8];  // broadcast
                short8 af[4];
                #pragma unroll
                for (int tm = 0; tm < 4; tm++) {
                    int f = fqa + tm * 16 + lm;
                    af[tm] = *(const short8*)&GS[f * 128 +
                             ((ks * 32 + lq * 8) ^ ((f & 7) << 3))];
                }
                short8 pb[4];
                #pragma unroll
                for (int tn = 0; tn < 4; tn++) {
                    ushort col = (ushort)(dqa + tn * 16 + lm);
                    union { ushort u[8]; short8 s; } b;
                    #pragma unroll
                    for (int q = 0; q < 8; q++)
                        b.u[q] = (dl8.u[q] == col) ? (ushort)0x3F80 : (ushort)0;
                    pb[tn] = b.s;
                }
                #pragma unroll
                for (int tm = 0; tm < 4; tm++)
                    #pragma unroll
                    for (int tn = 0; tn < 4; tn++)
                        accST[tm * 4 + tn] = __builtin_amdgcn_mfma_f32_16x16x32_bf16(
                            __builtin_bit_cast(bf16x8, af[tm]),
                            __builtin_bit_cast(bf16x8, pb[tn]),
                            accST[tm * 4 + tn], 0, 0, 0);
            }
            __syncthreads();                           // B: agg reads done

            if (more) {
                #pragma unroll
                for (int s = 0; s < 4; s++) {
                    rc4[s] = rcn[s];
                    ga[s][0].v = gan[s][0].v;
                    ga[s][1].v = gan[s][1].v;
                }
            }
        }

        // ---- pack accST -> Ssm[dst][f] (R8-verified swizzle, aliased) ----
        // C-frag (tm,tn) elem i: f = fqa+tm*16+lq*4+i, dst = dqa+tn*16+lm
        #pragma unroll
        for (int tm = 0; tm < 4; tm++)
            #pragma unroll
            for (int tn = 0; tn < 4; tn++) {
                f32x4 v = accST[tm * 4 + tn];
                union { unsigned u[2]; uint2v w; } pk;
                pk.u[0] = f2bf(v[0]) | (f2bf(v[1]) << 16);
                pk.u[1] = f2bf(v[2]) | (f2bf(v[3]) << 16);
                int dst = dqa + tn * 16 + lm;
                int f4 = fqa + tm * 16 + lq * 4;
                *(uint2v*)&GS[dst * 128 + (((f4 >> 3) ^ (dst & 15)) << 3) +
                              (f4 & 7)] = pk.w;
            }
        __syncthreads();                               // C: Ssm ready

        // ---- project: acc^T += wtr[r](A, global L2-hot) @ Ssm(B) ----
        const ushort* wp = wtr + ((size_t)r << 14);
        #pragma unroll
        for (int ks = 0; ks < 4; ks++) {
            short8 aw[4], bs[4];
            #pragma unroll
            for (int tm = 0; tm < 4; tm++) {
                int of = fqa + tm * 16 + lm;
                aw[tm] = *(const short8*)(wp + of * 128 + ks * 32 + lq * 8);
            }
            #pragma unroll
            for (int tn = 0; tn < 4; tn++) {
                int dst = dqa + tn * 16 + lm;
                bs[tn] = *(const short8*)&GS[dst * 128 +
                         (((ks * 4 + lq) ^ (dst & 15)) << 3)];
            }
            #pragma unroll
            for (int tm = 0; tm < 4; tm++)
                #pragma unroll
                for (int tn = 0; tn < 4; tn++)
                    acc[tm * 4 + tn] = __builtin_amdgcn_mfma_f32_16x16x32_bf16(
                        __builtin_bit_cast(bf16x8, aw[tm]),
                        __builtin_bit_cast(bf16x8, bs[tn]),
                        acc[tm * 4 + tn], 0, 0, 0);
        }
        __syncthreads();                               // D: Ssm free for next r
    }

    // ---- epilogue: acc^T frags -> float4 stores ----
    // acc (tm,tn) elem i: of = fqa+tm*16+lq*4+i, dst = dqa+tn*16+lm
    #pragma unroll
    for (int tn = 0; tn < 4; tn++) {
        int drow = base + dqa + tn * 16 + lm;
        if (drow < N) {
            #pragma unroll
            for (int tm = 0; tm < 4; tm++) {
                f32x4 v = acc[tm * 4 + tn];
                *(f32x4*)(out + (size_t)drow * FEAT + fqa + tm * 16 + lq * 4) = v;
            }
        }
    }
}

static inline size_t al256(size_t x) { return (x + 255) & ~(size_t)255; }

extern "C" void kernel_launch(void* const* d_in, const int* in_sizes, int n_in,
                              void* d_out, int out_size, void* d_ws,
                              size_t ws_size, hipStream_t stream) {
    const float* feat = (const float*)d_in[0];
    const float* weight = (const float*)d_in[1];
    const int* src = (const int*)d_in[2];
    const int* dst = (const int*)d_in[3];
    const int* et = (const int*)d_in[4];

    int nfeat = in_sizes[0];
    int N = nfeat / FEAT;                    // 100000
    int R = in_sizes[1] / (FEAT * FEAT);     // 8
    int E = in_sizes[2];                     // 1.6M
    int Npad = ((N + 127) / 128) * 128;
    int nblk = Npad / 128;                   // 782
    int NB = nblk * R;                       // 6256 buckets
    float* out = (float*)d_out;

    int sbits = 1;
    while ((1 << sbits) < N) sbits++;        // 17 for N=100000

    // ---- workspace layout (~28 MB) ----
    char* ws = (char*)d_ws;
    size_t o = 0;
    size_t cur_o  = o; o += al256((size_t)NB * 4);
    size_t recs_o = o; o += al256((size_t)NB * CAP * 4);
    size_t wtr_o  = o; o += al256((size_t)R * FEAT * FEAT * 2);
    size_t featb_o = o;

    int* cursor = (int*)(ws + cur_o);
    int* recs   = (int*)(ws + recs_o);
    ushort* wtr   = (ushort*)(ws + wtr_o);
    ushort* featb = (ushort*)(ws + featb_o);

    hipMemsetAsync(cursor, 0, (size_t)NB * 4, stream);

    int wtotal = R * FEAT * FEAT;
    cvt_w_kernel<<<(wtotal + 255) / 256, 256, 0, stream>>>(weight, wtr, wtotal);
    int n8 = nfeat / 8;
    cvt_feat_kernel<<<(n8 + 255) / 256, 256, 0, stream>>>(feat, featb, n8);

    scatter_kernel<<<512, 256, 0, stream>>>(dst, et, src, E, R, sbits,
                                            cursor, recs);

    fused_kernel<<<nblk, 256, 0, stream>>>(featb, wtr, recs, cursor,
                                           out, N, R, sbits);
}

// Round 10
// 485.717 us; speedup vs baseline: 1.5873x; 1.2008x over previous
//
#include <hip/hip_runtime.h>
#include <hip/hip_bf16.h>

// RGCN segment MM:  out[d] = sum_r ( sum_{e: dst=d, et=r} feat[src[e]] ) @ W[r]
// Bucket = (dst>>7)*R + et (6256 buckets) built by one bump-allocator scatter
// (rec = src | dl<<sbits). Fused kernel (256 thr, 4 waves, 64x64 quadrants),
// per (block of 128 dst, r):
//   per 128-edge chunk:
//     stage: edge-QUAD gathers (8x b128, held in ga) packed -> feat-major
//            Gt[f][e], XOR-swizzle idx = f*128 + (e ^ ((f&7)<<3)), b64 writes
//     AGGREGATE: accST[f][dst] += Gt(A, swz b128) @ onehot(B, regs from dlv)
//   per r: pack accST -> Ssm[dst][f] (swizzled, aliased on Gt);
//          PROJECT: acc^T[of][dst] += wtr[r](A, L2-hot global) @ Ssm(B).
// acc held across r; epilogue float4 stores.
//
// R10 lesson: budget at (256,2) = 256 unified regs/wave; 128 AGPR (acc+accST)
// leaves 128 arch. gan/rcn prefetch double-buffer blew it -> 423MB spills.
// R11: single ga buffer -- next-chunk gather issued AFTER barrier A directly
// into ga (dead there); next-R gather issued between pack and project. All
// loop barriers raw (lgkmcnt+s_barrier) so __syncthreads' vmcnt(0) drain
// can't serialize in-flight gathers. Arch liveness ~110 < 128 -> no spill.

#define FEAT 128
#define CAP 512          // records per bucket (lambda~256, 16 sigma headroom)
#define CHUNK 128

typedef __attribute__((ext_vector_type(8))) short short8;
typedef __attribute__((ext_vector_type(8))) __bf16 bf16x8;
typedef __attribute__((ext_vector_type(4))) float f32x4;
typedef __attribute__((ext_vector_type(2))) unsigned int uint2v;

union U8x16 { uint4 v; ushort us[8]; };

__device__ __forceinline__ unsigned f2bf(float x) {
    union { float f; unsigned u; } v; v.f = x;
    unsigned r = v.u + 0x7FFFu + ((v.u >> 16) & 1u);   // RNE
    return r >> 16;
}

__device__ __forceinline__ void raw_bar() {
    asm volatile("s_waitcnt lgkmcnt(0)" ::: "memory");
    __builtin_amdgcn_s_barrier();
    __builtin_amdgcn_sched_barrier(0);
}

// ---------------- conversions ----------------
__global__ void cvt_feat_kernel(const float* __restrict__ f,
                                ushort* __restrict__ o, int n8) {
    int i = blockIdx.x * blockDim.x + threadIdx.x;
    if (i >= n8) return;
    const float4* f4 = (const float4*)f;
    float4 a = f4[2 * i], b = f4[2 * i + 1];
    union { ushort u[8]; int4 v; } pk;
    pk.u[0] = f2bf(a.x); pk.u[1] = f2bf(a.y); pk.u[2] = f2bf(a.z); pk.u[3] = f2bf(a.w);
    pk.u[4] = f2bf(b.x); pk.u[5] = f2bf(b.y); pk.u[6] = f2bf(b.z); pk.u[7] = f2bf(b.w);
    ((int4*)o)[i] = pk.v;
}

// W[r][k][n] fp32 -> wt[r][n][k] bf16 (of-major, k contiguous)
__global__ void cvt_w_kernel(const float* __restrict__ w,
                             ushort* __restrict__ wt, int total) {
    int i = blockIdx.x * blockDim.x + threadIdx.x;
    if (i >= total) return;
    int r = i >> 14, n = (i >> 7) & 127, k = i & 127;
    wt[i] = (ushort)f2bf(w[(r << 14) + (k << 7) + n]);
}

// ---------------- bucketize edges (bump allocator) ----------------
__global__ void scatter_kernel(const int* __restrict__ dst,
                               const int* __restrict__ et,
                               const int* __restrict__ src, int E, int R,
                               int sbits, int* __restrict__ cursor,
                               int* __restrict__ recs) {
    int tid = blockIdx.x * blockDim.x + threadIdx.x;
    int stride = gridDim.x * blockDim.x;
    int nq = E >> 2;
    for (int i = tid; i < nq; i += stride) {
        int4 d4 = ((const int4*)dst)[i];
        int4 e4 = ((const int4*)et)[i];
        int4 s4 = ((const int4*)src)[i];
        int dd[4] = {d4.x, d4.y, d4.z, d4.w};
        int ee[4] = {e4.x, e4.y, e4.z, e4.w};
        int ss[4] = {s4.x, s4.y, s4.z, s4.w};
        #pragma unroll
        for (int s = 0; s < 4; s++) {
            int d = dd[s];
            int b = (d >> 7) * R + ee[s];
            int p = atomicAdd(&cursor[b], 1);
            if (p < CAP)
                __builtin_nontemporal_store(ss[s] | ((d & 127) << sbits),
                                            &recs[(size_t)b * CAP + p]);
        }
    }
    for (int i = (nq << 2) + tid; i < E; i += stride) {
        int d = dst[i];
        int b = (d >> 7) * R + et[i];
        int p = atomicAdd(&cursor[b], 1);
        if (p < CAP) recs[(size_t)b * CAP + p] = src[i] | ((d & 127) << sbits);
    }
}

// ---------------- fused aggregate + project ----------------
__global__ __launch_bounds__(256, 2)
void fused_kernel(const ushort* __restrict__ featb,
                  const ushort* __restrict__ wtr,
                  const int* __restrict__ recs,
                  const int* __restrict__ cursor,
                  float* __restrict__ out, int N, int R, int sbits) {
    __shared__ __align__(16) ushort GS[128 * 128];  // Gt[f][e] / Ssm[d][f], aliased
    __shared__ __align__(16) ushort dlv[CHUNK];     // dst-low per edge slot

    int t = threadIdx.x;
    int lane = t & 63, wid = t >> 6;
    int lm = lane & 15, lq = lane >> 4;    // MFMA fragment coords
    int qd = t & 31;                       // staging edge-quad (edges qd*4..+3)
    int fs = t >> 5;                       // staging feat block (feats fs*16..+15)
    int blk = blockIdx.x, base = blk * 128;
    int fqa = (wid >> 1) * 64;             // feat/of quadrant (A rows)
    int dqa = (wid & 1) * 64;              // dst quadrant (B cols)
    int smask = (1 << sbits) - 1;

    f32x4 acc[16];                         // out^T[of][dst], across all r
    #pragma unroll
    for (int i = 0; i < 16; i++) acc[i] = (f32x4){0.f, 0.f, 0.f, 0.f};

    int rc4[4]; U8x16 ga[4][2];

    // gather helper pattern is inlined at 3 sites (chunk0 preload, in-loop,
    // next-r preload) to keep all indices compile-time static.
    int ecnt = cursor[blk * R];
    if (ecnt < 0) ecnt = 0;
    if (ecnt > CAP) ecnt = CAP;
    const int* rb = recs + (size_t)(blk * R) * CAP;
    #pragma unroll
    for (int s = 0; s < 4; s++) {
        int j = qd * 4 + s;
        int rc = (j < ecnt) ? rb[j] : -1;
        rc4[s] = rc;
        #pragma unroll
        for (int h = 0; h < 2; h++)
            ga[s][h].v = (rc >= 0)
                ? *(const uint4*)(featb + (size_t)(rc & smask) * FEAT + fs * 16 + h * 8)
                : (uint4){0u, 0u, 0u, 0u};
    }

    for (int r = 0; r < R; r++) {
        f32x4 accST[16];                   // S^T[f][dst] for this r
        #pragma unroll
        for (int i = 0; i < 16; i++) accST[i] = (f32x4){0.f, 0.f, 0.f, 0.f};

        for (int c0 = 0; c0 < ecnt; c0 += CHUNK) {
            // ---- stage: quad-pack ga -> Gt[f][e], idx = f*128 + (e^((f&7)<<3)) ----
            #pragma unroll
            for (int h = 0; h < 2; h++)
                #pragma unroll
                for (int j = 0; j < 8; j++) {
                    int f = fs * 16 + h * 8 + j;       // f&7 == j
                    unsigned lo = (unsigned)ga[0][h].us[j] |
                                  ((unsigned)ga[1][h].us[j] << 16);
                    unsigned hi = (unsigned)ga[2][h].us[j] |
                                  ((unsigned)ga[3][h].us[j] << 16);
                    uint2v w; w[0] = lo; w[1] = hi;
                    *(uint2v*)&GS[f * 128 + ((qd * 4) ^ (j << 3))] = w;
                }
            if (fs == 0) {
                #pragma unroll
                for (int s = 0; s < 4; s++)
                    dlv[qd * 4 + s] = (rc4[s] >= 0)
                        ? (ushort)((rc4[s] >> sbits) & 127) : (ushort)0xFFFF;
            }
            raw_bar();                                 // A: Gt + dlv ready

            // ---- in-flight gather of next chunk directly into ga ----
            bool more = (c0 + CHUNK) < ecnt;
            if (more) {
                #pragma unroll
                for (int s = 0; s < 4; s++) {
                    int j = c0 + CHUNK + qd * 4 + s;
                    int rc = (j < ecnt) ? rb[j] : -1;
                    rc4[s] = rc;
                    #pragma unroll
                    for (int h = 0; h < 2; h++)
                        ga[s][h].v = (rc >= 0)
                            ? *(const uint4*)(featb +
                              (size_t)(rc & smask) * FEAT + fs * 16 + h * 8)
                            : (uint4){0u, 0u, 0u, 0u};
                }
            }

            // ---- aggregate: accST += Gt(A) @ onehot(B) ----
            #pragma unroll
            for (int ks = 0; ks < 4; ks++) {
                union { ushort u[8]; uint4 v; } dl8;
                dl8.v = *(const uint4*)&dlv[ks * 32 + lq * 8];  // broadcast
                short8 af[4];
                #pragma unroll
                for (int tm = 0; tm < 4; tm++) {
                    int f = fqa + tm * 16 + lm;
                    af[tm] = *(const short8*)&GS[f * 128 +
                             ((ks * 32 + lq * 8) ^ ((f & 7) << 3))];
                }
                short8 pb[4];
                #pragma unroll
                for (int tn = 0; tn < 4; tn++) {
                    ushort col = (ushort)(dqa + tn * 16 + lm);
                    union { ushort u[8]; short8 s; } b;
                    #pragma unroll
                    for (int q = 0; q < 8; q++)
                        b.u[q] = (dl8.u[q] == col) ? (ushort)0x3F80 : (ushort)0;
                    pb[tn] = b.s;
                }
                #pragma unroll
                for (int tm = 0; tm < 4; tm++)
                    #pragma unroll
                    for (int tn = 0; tn < 4; tn++)
                        accST[tm * 4 + tn] = __builtin_amdgcn_mfma_f32_16x16x32_bf16(
                            __builtin_bit_cast(bf16x8, af[tm]),
                            __builtin_bit_cast(bf16x8, pb[tn]),
                            accST[tm * 4 + tn], 0, 0, 0);
            }
            raw_bar();                                 // B: agg reads done
        }

        // ---- pack accST -> Ssm[dst][f] (swizzled, aliased on GS) ----
        // C-frag (tm,tn) elem i: f = fqa+tm*16+lq*4+i, dst = dqa+tn*16+lm
        #pragma unroll
        for (int tm = 0; tm < 4; tm++)
            #pragma unroll
            for (int tn = 0; tn < 4; tn++) {
                f32x4 v = accST[tm * 4 + tn];
                union { unsigned u[2]; uint2v w; } pk;
                pk.u[0] = f2bf(v[0]) | (f2bf(v[1]) << 16);
                pk.u[1] = f2bf(v[2]) | (f2bf(v[3]) << 16);
                int dst = dqa + tn * 16 + lm;
                int f4 = fqa + tm * 16 + lq * 4;
                *(uint2v*)&GS[dst * 128 + (((f4 >> 3) ^ (dst & 15)) << 3) +
                              (f4 & 7)] = pk.w;
            }
        raw_bar();                                     // C: Ssm ready

        // ---- preload next r's chunk 0 (hides under project) ----
        int ecnt_n = 0;
        const int* rb_n = rb;
        if (r + 1 < R) {
            ecnt_n = cursor[blk * R + r + 1];
            if (ecnt_n < 0) ecnt_n = 0;
            if (ecnt_n > CAP) ecnt_n = CAP;
            rb_n = recs + (size_t)(blk * R + r + 1) * CAP;
            #pragma unroll
            for (int s = 0; s < 4; s++) {
                int j = qd * 4 + s;
                int rc = (j < ecnt_n) ? rb_n[j] : -1;
                rc4[s] = rc;
                #pragma unroll
                for (int h = 0; h < 2; h++)
                    ga[s][h].v = (rc >= 0)
                        ? *(const uint4*)(featb +
                          (size_t)(rc & smask) * FEAT + fs * 16 + h * 8)
                        : (uint4){0u, 0u, 0u, 0u};
            }
        }

        // ---- project: acc^T += wtr[r](A, global L2-hot) @ Ssm(B) ----
        const ushort* wp = wtr + ((size_t)r << 14);
        #pragma unroll
        for (int ks = 0; ks < 4; ks++) {
            short8 aw[4], bs[4];
            #pragma unroll
            for (int tm = 0; tm < 4; tm++) {
                int of = fqa + tm * 16 + lm;
                aw[tm] = *(const short8*)(wp + of * 128 + ks * 32 + lq * 8);
            }
            #pragma unroll
            for (int tn = 0; tn < 4; tn++) {
                int dst = dqa + tn * 16 + lm;
                bs[tn] = *(const short8*)&GS[dst * 128 +
                         (((ks * 4 + lq) ^ (dst & 15)) << 3)];
            }
            #pragma unroll
            for (int tm = 0; tm < 4; tm++)
                #pragma unroll
                for (int tn = 0; tn < 4; tn++)
                    acc[tm * 4 + tn] = __builtin_amdgcn_mfma_f32_16x16x32_bf16(
                        __builtin_bit_cast(bf16x8, aw[tm]),
                        __builtin_bit_cast(bf16x8, bs[tn]),
                        acc[tm * 4 + tn], 0, 0, 0);
        }
        raw_bar();                                     // D: Ssm free for next r

        ecnt = ecnt_n;
        rb = rb_n;
    }

    // ---- epilogue: acc^T frags -> float4 stores ----
    // acc (tm,tn) elem i: of = fqa+tm*16+lq*4+i, dst = dqa+tn*16+lm
    #pragma unroll
    for (int tn = 0; tn < 4; tn++) {
        int drow = base + dqa + tn * 16 + lm;
        if (drow < N) {
            #pragma unroll
            for (int tm = 0; tm < 4; tm++) {
                f32x4 v = acc[tm * 4 + tn];
                *(f32x4*)(out + (size_t)drow * FEAT + fqa + tm * 16 + lq * 4) = v;
            }
        }
    }
}

static inline size_t al256(size_t x) { return (x + 255) & ~(size_t)255; }

extern "C" void kernel_launch(void* const* d_in, const int* in_sizes, int n_in,
                              void* d_out, int out_size, void* d_ws,
                              size_t ws_size, hipStream_t stream) {
    const float* feat = (const float*)d_in[0];
    const float* weight = (const float*)d_in[1];
    const int* src = (const int*)d_in[2];
    const int* dst = (const int*)d_in[3];
    const int* et = (const int*)d_in[4];

    int nfeat = in_sizes[0];
    int N = nfeat / FEAT;                    // 100000
    int R = in_sizes[1] / (FEAT * FEAT);     // 8
    int E = in_sizes[2];                     // 1.6M
    int Npad = ((N + 127) / 128) * 128;
    int nblk = Npad / 128;                   // 782
    int NB = nblk * R;                       // 6256 buckets
    float* out = (float*)d_out;

    int sbits = 1;
    while ((1 << sbits) < N) sbits++;        // 17 for N=100000

    // ---- workspace layout (~28 MB) ----
    char* ws = (char*)d_ws;
    size_t o = 0;
    size_t cur_o  = o; o += al256((size_t)NB * 4);
    size_t recs_o = o; o += al256((size_t)NB * CAP * 4);
    size_t wtr_o  = o; o += al256((size_t)R * FEAT * FEAT * 2);
    size_t featb_o = o;

    int* cursor = (int*)(ws + cur_o);
    int* recs   = (int*)(ws + recs_o);
    ushort* wtr   = (ushort*)(ws + wtr_o);
    ushort* featb = (ushort*)(ws + featb_o);

    hipMemsetAsync(cursor, 0, (size_t)NB * 4, stream);

    int wtotal = R * FEAT * FEAT;
    cvt_w_kernel<<<(wtotal + 255) / 256, 256, 0, stream>>>(weight, wtr, wtotal);
    int n8 = nfeat / 8;
    cvt_feat_kernel<<<(n8 + 255) / 256, 256, 0, stream>>>(feat, featb, n8);

    scatter_kernel<<<512, 256, 0, stream>>>(dst, et, src, E, R, sbits,
                                            cursor, recs);

    fused_kernel<<<nblk, 256, 0, stream>>>(featb, wtr, recs, cursor,
                                           out, N, R, sbits);
}